// Round 5
// baseline (959.524 us; speedup 1.0000x reference)
//
#include <hip/hip_runtime.h>

#define DIN 100
#define DD  64
#define NE  250000
#define NB  16
#define NN  50000
#define NR  500
#define NM  500000
#define NH  (NM + NN)

// workspace layout (float offsets). H doubles as TA (rows<nmax, in-place)
// and HU2 (rows >= NM, in-place).
#define H_OFF    64
#define TA2_OFF  (H_OFF + NH*DD)
#define RT_OFF   (TA2_OFF + NE*DD)
#define QT_OFF   (RT_OFF + 4*NR*DD)
#define LG_OFF   (QT_OFF + 4*NB*DD)

// k_tf grid segmentation (pool0 does 2 GEMMs -> 2:1:~1/6 work split)
#define PA 320
#define PB 160
#define PC 32

#define XT_STRIDE 260   // %32==4 -> 2-way (free) on tiled reads; 16B-aligned rows

// k_proj pipelined chunking: 6x16k + 4k tail, double-buffered.
#define PCH  16
#define NPCH 7
// k_tf pipelined chunking: 8x8k, double-buffered.
#define TCH  8
#define NTCH 8

__device__ __forceinline__ void fma4x4(const float4 x, const float4 w, float4 acc[4]) {
  acc[0].x += x.x*w.x; acc[0].y += x.x*w.y; acc[0].z += x.x*w.z; acc[0].w += x.x*w.w;
  acc[1].x += x.y*w.x; acc[1].y += x.y*w.y; acc[1].z += x.y*w.z; acc[1].w += x.y*w.w;
  acc[2].x += x.z*w.x; acc[2].y += x.z*w.y; acc[2].z += x.z*w.z; acc[2].w += x.z*w.w;
  acc[3].x += x.w*w.x; acc[3].y += x.w*w.y; acc[3].z += x.w*w.z; acc[3].w += x.w*w.w;
}

__device__ __forceinline__ float4 leaky4(float4 v) {
  v.x = v.x > 0.f ? v.x : 0.2f*v.x;
  v.y = v.y > 0.f ? v.y : 0.2f*v.y;
  v.z = v.z > 0.f ? v.z : 0.2f*v.z;
  v.w = v.w > 0.f ? v.w : 0.2f*v.w;
  return v;
}

__global__ void k_init(int* wsI, float* bsum) {
  if (threadIdx.x == 0) { wsI[0] = 0x7fffffff; wsI[1] = 0; }
  if (threadIdx.x < NB) bsum[threadIdx.x] = 0.f;
}

__global__ void k_limits(const int* __restrict__ edges, int* __restrict__ wsI) {
  int i = blockIdx.x * blockDim.x + threadIdx.x;
  int mn = 0x7fffffff, mx = -1;
  if (i < NE) { int v = edges[i*8 + 7]; mn = v; mx = v; }
  for (int off = 32; off > 0; off >>= 1) {
    mn = min(mn, __shfl_down(mn, off));
    mx = max(mx, __shfl_down(mx, off));
  }
  if ((threadIdx.x & 63) == 0) {
    atomicMin(&wsI[0], mn);
    atomicMax(&wsI[1], mx + 1);
  }
}

// one 64-thread block per (rel row | batch row): builds per-rel / per-batch tables
__global__ void k_tables(const float* __restrict__ rtab,
                         const float* __restrict__ qh, const float* __restrict__ qr,
                         const float* __restrict__ pW, const float* __restrict__ pb,
                         const float* __restrict__ g1_lW, const float* __restrict__ g1_lb,
                         const float* __restrict__ g1_rW, const float* __restrict__ g1_rb,
                         const float* __restrict__ g2_lW, const float* __restrict__ g2_lb,
                         const float* __restrict__ g2_rW, const float* __restrict__ g2_rb,
                         float* __restrict__ rT, float* __restrict__ qT) {
  __shared__ float xs[DIN], xs2[DIN], ps[DD], ps2[DD];
  const int d = threadIdx.x;
  const int blk = blockIdx.x;
  if (blk < NR) {
    for (int k = d; k < DIN; k += 64) xs[k] = rtab[blk*DIN + k];
    __syncthreads();
    float a = pb[d];
    for (int k = 0; k < DIN; ++k) a += xs[k] * pW[k*DD + d];
    ps[d] = tanhf(a);
    __syncthreads();
    float o1 = 0.f, o2 = 0.f, o3 = 0.f, o4 = 0.f;
    for (int k = 0; k < DD; ++k) {
      float p = ps[k];
      o1 += p * g1_lW[(DD + k)*DD + d];
      o2 += p * g1_rW[(DD + k)*DD + d];
      o3 += p * g2_lW[(DD + k)*DD + d];
      o4 += p * g2_rW[(DD + k)*DD + d];
    }
    rT[(0*NR + blk)*DD + d] = o1;
    rT[(1*NR + blk)*DD + d] = o2;
    rT[(2*NR + blk)*DD + d] = o3;
    rT[(3*NR + blk)*DD + d] = o4;
  } else {
    const int b = blk - NR;
    for (int k = d; k < DIN; k += 64) { xs[k] = qh[b*DIN + k]; xs2[k] = qr[b*DIN + k]; }
    __syncthreads();
    float a = pb[d], a2 = pb[d];
    for (int k = 0; k < DIN; ++k) { a += xs[k]*pW[k*DD + d]; a2 += xs2[k]*pW[k*DD + d]; }
    ps[d] = tanhf(a); ps2[d] = tanhf(a2);
    __syncthreads();
    float o1 = g1_lb[d], o2 = g1_rb[d], o3 = g2_lb[d], o4 = g2_rb[d];
    for (int k = 0; k < DD; ++k) {
      float p = ps[k], p2 = ps2[k];
      o1 += p * g1_lW[(2*DD + k)*DD + d] + p2 * g1_lW[(3*DD + k)*DD + d];
      o2 += p * g1_rW[(2*DD + k)*DD + d] + p2 * g1_rW[(3*DD + k)*DD + d];
      o3 += p * g2_lW[(2*DD + k)*DD + d] + p2 * g2_lW[(3*DD + k)*DD + d];
      o4 += p * g2_rW[(2*DD + k)*DD + d] + p2 * g2_rW[(3*DD + k)*DD + d];
    }
    qT[(0*NB + b)*DD + d] = o1;
    qT[(1*NB + b)*DD + d] = o2;
    qT[(2*NB + b)*DD + d] = o3;
    qT[(3*NB + b)*DD + d] = o4;
  }
}

// persistent proj, 256-row tiles, 8x8 register tile per thread.
// v5: double-buffered staging pipeline. Rounds 0/3/4 showed time invariant
// to occupancy/barrier-count/FETCH at 41% VALU -> the stall is the barrier
// DRAIN (all waves wait on the slowest stage-loader's ~900cyc scattered
// loads every chunk). Pipeline: issue chunk c+1 loads -> compute chunk c
// -> ds_write c+1 -> one barrier. Loads get a full compute phase of slack.
// pWs back in LDS (round 4: VMEM-w was worse). LDS 58.9KB -> 2 blocks/CU.
__global__ __launch_bounds__(256, 2)
void k_proj(const float* __restrict__ hcon, const float* __restrict__ huncon,
            const float* __restrict__ pW, const float* __restrict__ pb,
            const int* __restrict__ lim, float* __restrict__ H) {
  __shared__ __align__(16) float pWs[DIN*DD];             // 25.6 KB
  __shared__ __align__(16) float Xt[2][PCH][XT_STRIDE];   // 33.3 KB
  const int tid = threadIdx.x;
  for (int i = tid; i < DIN*DD; i += 256) pWs[i] = pW[i];
  const int tc = tid & 7, tr = tid >> 3;
  const int c0 = tc << 3;
  const float4 pb0 = *(const float4*)&pb[c0];
  const float4 pb1 = *(const float4*)&pb[c0 + 4];
  const int nmax = lim[1];
  const int t_lo = (nmax + 255) >> 8;
  const int NT   = t_lo + ((NN + 255) >> 8);
  for (int t = blockIdx.x; t < NT; t += gridDim.x) {
    const int row0 = (t < t_lo) ? (t << 8) : (NM + ((t - t_lo) << 8));
    const int myrow = row0 + tid;                     // staging: one row per thread
    const float4* src4 = nullptr;
    if (myrow < NH)
      src4 = (const float4*)((myrow < NM) ? &hcon[(size_t)myrow*DIN]
                                          : &huncon[(size_t)(myrow - NM)*DIN]);
    float4 acc[2][2][4];
    #pragma unroll
    for (int a = 0; a < 2; ++a)
      #pragma unroll
      for (int b = 0; b < 2; ++b)
        #pragma unroll
        for (int i = 0; i < 4; ++i) acc[a][b][i] = make_float4(0.f,0.f,0.f,0.f);
    float4 rb[4];
    if (src4) { rb[0] = src4[0]; rb[1] = src4[1]; rb[2] = src4[2]; rb[3] = src4[3]; }
    __syncthreads();                     // prev tile fully consumed Xt (both bufs)
    if (src4) {
      #pragma unroll
      for (int j = 0; j < 4; ++j) {
        Xt[0][4*j+0][tid] = rb[j].x; Xt[0][4*j+1][tid] = rb[j].y;
        Xt[0][4*j+2][tid] = rb[j].z; Xt[0][4*j+3][tid] = rb[j].w;
      }
      rb[0] = src4[4]; rb[1] = src4[5]; rb[2] = src4[6]; rb[3] = src4[7];
    }
    __syncthreads();                     // Xt[0] (and pWs, first iter) ready
    for (int ch = 0; ch < NPCH; ++ch) {
      const int kb  = ch * PCH;
      const int buf = ch & 1;
      if (ch < NPCH - 1) {
        #pragma unroll 4
        for (int k = 0; k < PCH; ++k) {
          float4 x0 = *(const float4*)&Xt[buf][k][tr*8];
          float4 x1 = *(const float4*)&Xt[buf][k][tr*8 + 4];
          float4 w0 = *(const float4*)&pWs[(kb + k)*DD + c0];
          float4 w1 = *(const float4*)&pWs[(kb + k)*DD + c0 + 4];
          fma4x4(x0, w0, acc[0][0]); fma4x4(x0, w1, acc[0][1]);
          fma4x4(x1, w0, acc[1][0]); fma4x4(x1, w1, acc[1][1]);
        }
      } else {                                        // tail: 4 k's
        #pragma unroll
        for (int k = 0; k < 4; ++k) {
          float4 x0 = *(const float4*)&Xt[buf][k][tr*8];
          float4 x1 = *(const float4*)&Xt[buf][k][tr*8 + 4];
          float4 w0 = *(const float4*)&pWs[(kb + k)*DD + c0];
          float4 w1 = *(const float4*)&pWs[(kb + k)*DD + c0 + 4];
          fma4x4(x0, w0, acc[0][0]); fma4x4(x0, w1, acc[0][1]);
          fma4x4(x1, w0, acc[1][0]); fma4x4(x1, w1, acc[1][1]);
        }
      }
      if (ch + 1 < NPCH) {
        if (src4) {
          const int n4 = (ch + 1 == NPCH - 1) ? 1 : 4;   // tail chunk = 4 floats
          #pragma unroll
          for (int j = 0; j < 4; ++j) if (j < n4) {
            Xt[buf^1][4*j+0][tid] = rb[j].x; Xt[buf^1][4*j+1][tid] = rb[j].y;
            Xt[buf^1][4*j+2][tid] = rb[j].z; Xt[buf^1][4*j+3][tid] = rb[j].w;
          }
          if (ch + 2 < NPCH) {
            const int m4 = (ch + 2 == NPCH - 1) ? 1 : 4;
            #pragma unroll
            for (int j = 0; j < 4; ++j) if (j < m4) rb[j] = src4[(ch + 2)*4 + j];
          }
        }
        __syncthreads();
      }
    }
    #pragma unroll
    for (int a = 0; a < 2; ++a)
      #pragma unroll
      for (int i = 0; i < 4; ++i) {
        int row = row0 + tr*8 + a*4 + i;
        if (row < NH) {
          float4 o0, o1;
          o0.x = tanhf(acc[a][0][i].x + pb0.x);
          o0.y = tanhf(acc[a][0][i].y + pb0.y);
          o0.z = tanhf(acc[a][0][i].z + pb0.z);
          o0.w = tanhf(acc[a][0][i].w + pb0.w);
          o1.x = tanhf(acc[a][1][i].x + pb1.x);
          o1.y = tanhf(acc[a][1][i].y + pb1.y);
          o1.z = tanhf(acc[a][1][i].z + pb1.z);
          o1.w = tanhf(acc[a][1][i].w + pb1.w);
          *(float4*)&H[row*DD + c0]     = o0;
          *(float4*)&H[row*DD + c0 + 4] = o1;
        }
      }
  }
}

// persistent transform, 256-row tiles, 8x8 register tile, weights in LDS.
// v5: same double-buffered pipeline as k_proj (8 chunks of 8 k, Ht[2][8]).
// pool 0: rows<nvi : TA=H@W1a (in place), TA2=H@W2a
// pool 1: rows in [nvi,nmax): TA=H@W1b (in place)
// pool 2: huncon rows: HU2=H@g2_rW (in place)
__global__ __launch_bounds__(256, 2)
void k_tf(const float* __restrict__ g1_lW, const float* __restrict__ g1_rW,
          const float* __restrict__ g2_lW, const float* __restrict__ g2_rW,
          const int* __restrict__ lim,
          float* __restrict__ H, float* __restrict__ TA2) {
  __shared__ __align__(16) float Ws0[DD*DD];              // 16 KB
  __shared__ __align__(16) float Ws1[DD*DD];              // 16 KB
  __shared__ __align__(16) float Ht[2][TCH][XT_STRIDE];   // 16.6 KB
  const int tid = threadIdx.x;
  const int nvi  = lim[0];
  const int nmax = lim[1];
  int pool, pbase, pgrid;
  if (blockIdx.x < PA)           { pool = 0; pbase = blockIdx.x;           pgrid = PA; }
  else if (blockIdx.x < PA + PB) { pool = 1; pbase = blockIdx.x - PA;      pgrid = PB; }
  else                           { pool = 2; pbase = blockIdx.x - PA - PB; pgrid = PC; }
  if (pool == 0) {
    for (int i = tid; i < DD*DD; i += 256) { Ws0[i] = g1_lW[i]; Ws1[i] = g2_lW[i]; }
  } else if (pool == 1) {
    for (int i = tid; i < DD*DD; i += 256) Ws0[i] = g1_rW[i];
  } else {
    for (int i = tid; i < DD*DD; i += 256) Ws0[i] = g2_rW[i];
  }
  int t_begin, t_count, row_base;
  if (pool == 0)      { t_begin = 0;        t_count = (nvi + 255) >> 8;                 row_base = 0;  }
  else if (pool == 1) { t_begin = nvi >> 8; t_count = ((nmax + 255) >> 8) - (nvi >> 8); row_base = 0;  }
  else                { t_begin = 0;        t_count = (NN + 255) >> 8;                  row_base = NM; }
  const int tc = tid & 7, tr = tid >> 3;
  const int c0 = tc << 3;
  __syncthreads();   // Ws ready
  for (int tt = pbase; tt < t_count; tt += pgrid) {
    const int row0 = row_base + ((t_begin + tt) << 8);
    const int myrow = row0 + tid;
    const float4* H4 = (myrow < NH) ? (const float4*)&H[(size_t)myrow*DD] : nullptr;
    float4 a0[2][2][4], a1[2][2][4];
    #pragma unroll
    for (int a = 0; a < 2; ++a)
      #pragma unroll
      for (int b = 0; b < 2; ++b)
        #pragma unroll
        for (int i = 0; i < 4; ++i) {
          a0[a][b][i] = make_float4(0.f,0.f,0.f,0.f);
          a1[a][b][i] = make_float4(0.f,0.f,0.f,0.f);
        }
    float4 rb[2];
    if (H4) { rb[0] = H4[0]; rb[1] = H4[1]; }
    __syncthreads();                    // prev tile fully consumed Ht
    if (H4) {
      #pragma unroll
      for (int j = 0; j < 2; ++j) {
        Ht[0][4*j+0][tid] = rb[j].x; Ht[0][4*j+1][tid] = rb[j].y;
        Ht[0][4*j+2][tid] = rb[j].z; Ht[0][4*j+3][tid] = rb[j].w;
      }
      rb[0] = H4[2]; rb[1] = H4[3];
    }
    __syncthreads();                    // Ht[0] ready
    for (int ch = 0; ch < NTCH; ++ch) {
      const int kb  = ch * TCH;
      const int buf = ch & 1;
      if (pool == 0) {
        #pragma unroll
        for (int k = 0; k < TCH; ++k) {
          float4 x0 = *(const float4*)&Ht[buf][k][tr*8];
          float4 x1 = *(const float4*)&Ht[buf][k][tr*8 + 4];
          float4 w0 = *(const float4*)&Ws0[(kb + k)*DD + c0];
          float4 w1 = *(const float4*)&Ws0[(kb + k)*DD + c0 + 4];
          float4 u0 = *(const float4*)&Ws1[(kb + k)*DD + c0];
          float4 u1 = *(const float4*)&Ws1[(kb + k)*DD + c0 + 4];
          fma4x4(x0, w0, a0[0][0]); fma4x4(x0, w1, a0[0][1]);
          fma4x4(x1, w0, a0[1][0]); fma4x4(x1, w1, a0[1][1]);
          fma4x4(x0, u0, a1[0][0]); fma4x4(x0, u1, a1[0][1]);
          fma4x4(x1, u0, a1[1][0]); fma4x4(x1, u1, a1[1][1]);
        }
      } else {
        #pragma unroll
        for (int k = 0; k < TCH; ++k) {
          float4 x0 = *(const float4*)&Ht[buf][k][tr*8];
          float4 x1 = *(const float4*)&Ht[buf][k][tr*8 + 4];
          float4 w0 = *(const float4*)&Ws0[(kb + k)*DD + c0];
          float4 w1 = *(const float4*)&Ws0[(kb + k)*DD + c0 + 4];
          fma4x4(x0, w0, a0[0][0]); fma4x4(x0, w1, a0[0][1]);
          fma4x4(x1, w0, a0[1][0]); fma4x4(x1, w1, a0[1][1]);
        }
      }
      if (ch + 1 < NTCH) {
        if (H4) {
          #pragma unroll
          for (int j = 0; j < 2; ++j) {
            Ht[buf^1][4*j+0][tid] = rb[j].x; Ht[buf^1][4*j+1][tid] = rb[j].y;
            Ht[buf^1][4*j+2][tid] = rb[j].z; Ht[buf^1][4*j+3][tid] = rb[j].w;
          }
          if (ch + 2 < NTCH) { rb[0] = H4[(ch+2)*2]; rb[1] = H4[(ch+2)*2 + 1]; }
        }
        __syncthreads();
      }
    }
    #pragma unroll
    for (int a = 0; a < 2; ++a)
      #pragma unroll
      for (int i = 0; i < 4; ++i) {
        int row = row0 + tr*8 + a*4 + i;
        bool ok;
        if (pool == 0)      ok = (row < nvi);
        else if (pool == 1) ok = (row >= nvi && row < nmax);
        else                ok = (row < NH);
        if (ok) {
          *(float4*)&H[row*DD + c0]     = a0[a][0][i];
          *(float4*)&H[row*DD + c0 + 4] = a0[a][1][i];
          if (pool == 0) {
            *(float4*)&TA2[row*DD + c0]     = a1[a][0][i];
            *(float4*)&TA2[row*DD + c0 + 4] = a1[a][1][i];
          }
        }
      }
  }
}

// persistent edge kernel: cW1/cW2 transposed + cb resident in LDS.
__global__ __launch_bounds__(256, 2)
void k_edges(const int* __restrict__ edges,
             const float* __restrict__ TA, const float* __restrict__ TA2,
             const float* __restrict__ HU2,
             const float* __restrict__ rT, const float* __restrict__ qT,
             const float* __restrict__ cW1, const float* __restrict__ cb1,
             const float* __restrict__ cW2, const float* __restrict__ cb2,
             float* __restrict__ logits) {
  __shared__ __align__(16) float Wt1s[DD*68];
  __shared__ __align__(16) float Wt2s[DD*68];
  __shared__ __align__(16) float Lt[DD][68];
  __shared__ __align__(16) float Rt[DD][68];
  __shared__ __align__(16) float4 cbs4[2][16];
  __shared__ float lg[64];
  __shared__ int   se[64*8];
  const int tid = threadIdx.x;
  for (int i = tid; i < DD*DD; i += 256) {
    int k = i >> 6, d = i & 63;
    Wt1s[d*68 + k] = cW1[i];   // Wt[d][k] = cW[k][d]
    Wt2s[d*68 + k] = cW2[i];
  }
  if (tid < 16) {
    cbs4[0][tid] = *(const float4*)&cb1[tid*4];
    cbs4[1][tid] = *(const float4*)&cb2[tid*4];
  }
  const int e   = tid >> 2;
  const int d0  = (tid & 3) * 16;
  const int ee0 = (tid & 15) << 2;
  const int k0  = (tid >> 4) << 2;
  __syncthreads();
  const int NT = (NE + 63) / 64;
  for (int tile = blockIdx.x; tile < NT; tile += gridDim.x) {
    const int e0 = tile * 64;
    const int ecnt = min(64, NE - e0);
    for (int i = tid; i < 64*8; i += 256) se[i] = (i < ecnt*8) ? edges[e0*8 + i] : 0;
    if (tid < 64) lg[tid] = 0.f;
    __syncthreads();
    const int rel = se[e*8 + 3];
    const int eg  = se[e*8 + 0];
    const int li  = se[e*8 + 6];
    for (int g = 0; g < 2; ++g) {
      const float* Lb = g ? TA2 : TA;
      const float* Rb = g ? HU2 : TA;
      const float* rL = rT + (g ? 2*NR*DD : 0);
      const float* rR = rT + (g ? 3*NR*DD : 1*NR*DD);
      const float* qL = qT + (g ? 2*NB*DD : 0);
      const float* qR = qT + (g ? 3*NB*DD : 1*NB*DD);
      const float* Wts = g ? Wt2s : Wt1s;
      const int ri = g ? se[e*8 + 2] : se[e*8 + 7];
      float cbp = 0.f;
      #pragma unroll
      for (int di = 0; di < 4; ++di) {
        const int d = d0 + 4*di;
        float4 l = *(const float4*)&Lb[li*DD + d];
        float4 t = *(const float4*)&rL[rel*DD + d];
        float4 u = *(const float4*)&qL[eg*DD + d];
        l.x += t.x + u.x; l.y += t.y + u.y; l.z += t.z + u.z; l.w += t.w + u.w;
        l = leaky4(l);
        Lt[d+0][e] = l.x; Lt[d+1][e] = l.y; Lt[d+2][e] = l.z; Lt[d+3][e] = l.w;
        float4 c = cbs4[g][d >> 2];
        cbp += l.x*c.x + l.y*c.y + l.z*c.z + l.w*c.w;
        float4 r = *(const float4*)&Rb[ri*DD + d];
        t = *(const float4*)&rR[rel*DD + d];
        u = *(const float4*)&qR[eg*DD + d];
        r.x += t.x + u.x; r.y += t.y + u.y; r.z += t.z + u.z; r.w += t.w + u.w;
        r = leaky4(r);
        Rt[d+0][e] = r.x; Rt[d+1][e] = r.y; Rt[d+2][e] = r.z; Rt[d+3][e] = r.w;
      }
      atomicAdd(&lg[e], cbp);
      __syncthreads();
      float4 z[4] = {{0,0,0,0},{0,0,0,0},{0,0,0,0},{0,0,0,0}};
      for (int d = 0; d < DD; ++d) {
        float4 x = *(const float4*)&Lt[d][ee0];
        float4 w = *(const float4*)&Wts[d*68 + k0];
        fma4x4(x, w, z);
      }
      {
        float4 r0v = *(const float4*)&Rt[k0+0][ee0];
        float4 r1v = *(const float4*)&Rt[k0+1][ee0];
        float4 r2v = *(const float4*)&Rt[k0+2][ee0];
        float4 r3v = *(const float4*)&Rt[k0+3][ee0];
        float p0 = z[0].x*r0v.x + z[0].y*r1v.x + z[0].z*r2v.x + z[0].w*r3v.x;
        float p1 = z[1].x*r0v.y + z[1].y*r1v.y + z[1].z*r2v.y + z[1].w*r3v.y;
        float p2 = z[2].x*r0v.z + z[2].y*r1v.z + z[2].z*r2v.z + z[2].w*r3v.z;
        float p3 = z[3].x*r0v.w + z[3].y*r1v.w + z[3].z*r2v.w + z[3].w*r3v.w;
        atomicAdd(&lg[ee0+0], p0);
        atomicAdd(&lg[ee0+1], p1);
        atomicAdd(&lg[ee0+2], p2);
        atomicAdd(&lg[ee0+3], p3);
      }
      __syncthreads();
    }
    if (tid < ecnt) logits[e0 + tid] = lg[tid];
    __syncthreads();
  }
}

__global__ void k_softmax(const int* __restrict__ edges, const float* __restrict__ logits,
                          const float* __restrict__ na, float* __restrict__ out) {
  int e = blockIdx.x * blockDim.x + threadIdx.x;
  if (e >= NE) return;
  int seg = edges[e*8 + 4];
  if (e > 0 && edges[(e-1)*8 + 4] == seg) return;  // not a segment head
  int j = e;
  float m = -1e30f;
  while (j < NE && edges[j*8 + 4] == seg) { m = fmaxf(m, logits[j]); ++j; }
  float s = 0.f;
  for (int t = e; t < j; ++t) s += expf(logits[t] - m);
  int eg = edges[e*8 + 0], vi = edges[e*8 + 1];
  float scale = na[eg*NN + vi] / s;
  for (int t = e; t < j; ++t) {
    int vj = edges[t*8 + 2];
    __hip_atomic_fetch_add(&out[eg*NN + vj], expf(logits[t] - m) * scale,
                           __ATOMIC_RELAXED, __HIP_MEMORY_SCOPE_AGENT);
  }
}

__global__ void k_rowsum(const float* __restrict__ out, float* __restrict__ bsum) {
  int b = blockIdx.y;
  float s = 0.f;
  for (int n = blockIdx.x * blockDim.x + threadIdx.x; n < NN; n += gridDim.x * blockDim.x)
    s += out[b*NN + n];
  for (int off = 32; off > 0; off >>= 1) s += __shfl_down(s, off);
  if ((threadIdx.x & 63) == 0)
    __hip_atomic_fetch_add(&bsum[b], s, __ATOMIC_RELAXED, __HIP_MEMORY_SCOPE_AGENT);
}

__global__ void k_div(float* __restrict__ out, const float* __restrict__ bsum) {
  int i = blockIdx.x * blockDim.x + threadIdx.x;
  if (i < NB*NN) out[i] /= bsum[i / NN];
}

extern "C" void kernel_launch(void* const* d_in, const int* in_sizes, int n_in,
                              void* d_out, int out_size, void* d_ws, size_t ws_size,
                              hipStream_t stream) {
  (void)in_sizes; (void)n_in; (void)out_size; (void)ws_size;
  const float* na     = (const float*)d_in[0];
  const int*   edges  = (const int*)  d_in[1];
  const float* huncon = (const float*)d_in[2];
  const float* hcon   = (const float*)d_in[3];
  const float* rtab   = (const float*)d_in[4];
  const float* qh     = (const float*)d_in[5];
  const float* qr     = (const float*)d_in[6];
  const float* pW     = (const float*)d_in[7];
  const float* pb     = (const float*)d_in[8];
  const float* g1_lW  = (const float*)d_in[9];
  const float* g1_lb  = (const float*)d_in[10];
  const float* g1_rW  = (const float*)d_in[11];
  const float* g1_rb  = (const float*)d_in[12];
  const float* g1_cW  = (const float*)d_in[13];
  const float* g1_cb  = (const float*)d_in[14];
  const float* g2_lW  = (const float*)d_in[15];
  const float* g2_lb  = (const float*)d_in[16];
  const float* g2_rW  = (const float*)d_in[17];
  const float* g2_rb  = (const float*)d_in[18];
  const float* g2_cW  = (const float*)d_in[19];
  const float* g2_cb  = (const float*)d_in[20];
  float* out  = (float*)d_out;
  float* ws   = (float*)d_ws;
  int*   wsI  = (int*)d_ws;
  float* bsum = ws + 16;
  float* H    = ws + H_OFF;            // TA in-place; HU2 = H + NM*DD
  float* TA2  = ws + TA2_OFF;
  float* rT   = ws + RT_OFF;
  float* qT   = ws + QT_OFF;
  float* lgp  = ws + LG_OFF;

  hipMemsetAsync(d_out, 0, (size_t)NB*NN*sizeof(float), stream);
  k_init<<<1, 64, 0, stream>>>(wsI, bsum);
  k_limits<<<(NE + 255)/256, 256, 0, stream>>>(edges, wsI);
  k_tables<<<NR + NB, 64, 0, stream>>>(rtab, qh, qr, pW, pb,
                                       g1_lW, g1_lb, g1_rW, g1_rb,
                                       g2_lW, g2_lb, g2_rW, g2_rb, rT, qT);
  k_proj<<<768, 256, 0, stream>>>(hcon, huncon, pW, pb, wsI, H);
  k_tf<<<PA + PB + PC, 256, 0, stream>>>(g1_lW, g1_rW, g2_lW, g2_rW, wsI, H, TA2);
  k_edges<<<512, 256, 0, stream>>>(edges, H, TA2, H + NM*DD, rT, qT,
                                   g1_cW, g1_cb, g2_cW, g2_cb, lgp);
  k_softmax<<<(NE + 255)/256, 256, 0, stream>>>(edges, lgp, na, out);
  k_rowsum<<<dim3(32, 16), 256, 0, stream>>>(out, bsum);
  k_div<<<(NB*NN + 255)/256, 256, 0, stream>>>(out, bsum);
}

// Round 6
// 807.657 us; speedup vs baseline: 1.1880x; 1.1880x over previous
//
#include <hip/hip_runtime.h>

#define DIN 100
#define DD  64
#define NE  250000
#define NB  16
#define NN  50000
#define NR  500
#define NM  500000
#define NH  (NM + NN)

// workspace layout (float offsets). H doubles as TA (rows<nmax, in-place)
// and HU2 (rows >= NM, in-place).
#define H_OFF    64
#define TA2_OFF  (H_OFF + NH*DD)
#define RT_OFF   (TA2_OFF + NE*DD)
#define QT_OFF   (RT_OFF + 4*NR*DD)
#define LG_OFF   (QT_OFF + 4*NB*DD)

// k_tf grid segmentation (pool0 does 2 GEMMs -> 2:1:~1/6 work split)
#define PA 320
#define PB 160
#define PC 32

#define XT_STRIDE 260   // %32==4 -> 2-way (free) on tiled reads; 16B-aligned rows

// k_proj v6: 64-row tiles, row-major LDS (104-float padded rows), XOR-swizzled
#define PROJ_LDSF (64*104)    // floats per staging buffer (26.62 KB)

__device__ __forceinline__ void fma4x4(const float4 x, const float4 w, float4 acc[4]) {
  acc[0].x += x.x*w.x; acc[0].y += x.x*w.y; acc[0].z += x.x*w.z; acc[0].w += x.x*w.w;
  acc[1].x += x.y*w.x; acc[1].y += x.y*w.y; acc[1].z += x.y*w.z; acc[1].w += x.y*w.w;
  acc[2].x += x.z*w.x; acc[2].y += x.z*w.y; acc[2].z += x.z*w.z; acc[2].w += x.z*w.w;
  acc[3].x += x.w*w.x; acc[3].y += x.w*w.y; acc[3].z += x.w*w.z; acc[3].w += x.w*w.w;
}

__device__ __forceinline__ float4 leaky4(float4 v) {
  v.x = v.x > 0.f ? v.x : 0.2f*v.x;
  v.y = v.y > 0.f ? v.y : 0.2f*v.y;
  v.z = v.z > 0.f ? v.z : 0.2f*v.z;
  v.w = v.w > 0.f ? v.w : 0.2f*v.w;
  return v;
}

__global__ void k_init(int* wsI, float* bsum) {
  if (threadIdx.x == 0) { wsI[0] = 0x7fffffff; wsI[1] = 0; }
  if (threadIdx.x < NB) bsum[threadIdx.x] = 0.f;
}

__global__ void k_limits(const int* __restrict__ edges, int* __restrict__ wsI) {
  int i = blockIdx.x * blockDim.x + threadIdx.x;
  int mn = 0x7fffffff, mx = -1;
  if (i < NE) { int v = edges[i*8 + 7]; mn = v; mx = v; }
  for (int off = 32; off > 0; off >>= 1) {
    mn = min(mn, __shfl_down(mn, off));
    mx = max(mx, __shfl_down(mx, off));
  }
  if ((threadIdx.x & 63) == 0) {
    atomicMin(&wsI[0], mn);
    atomicMax(&wsI[1], mx + 1);
  }
}

// one 64-thread block per (rel row | batch row): builds per-rel / per-batch tables
__global__ void k_tables(const float* __restrict__ rtab,
                         const float* __restrict__ qh, const float* __restrict__ qr,
                         const float* __restrict__ pW, const float* __restrict__ pb,
                         const float* __restrict__ g1_lW, const float* __restrict__ g1_lb,
                         const float* __restrict__ g1_rW, const float* __restrict__ g1_rb,
                         const float* __restrict__ g2_lW, const float* __restrict__ g2_lb,
                         const float* __restrict__ g2_rW, const float* __restrict__ g2_rb,
                         float* __restrict__ rT, float* __restrict__ qT) {
  __shared__ float xs[DIN], xs2[DIN], ps[DD], ps2[DD];
  const int d = threadIdx.x;
  const int blk = blockIdx.x;
  if (blk < NR) {
    for (int k = d; k < DIN; k += 64) xs[k] = rtab[blk*DIN + k];
    __syncthreads();
    float a = pb[d];
    for (int k = 0; k < DIN; ++k) a += xs[k] * pW[k*DD + d];
    ps[d] = tanhf(a);
    __syncthreads();
    float o1 = 0.f, o2 = 0.f, o3 = 0.f, o4 = 0.f;
    for (int k = 0; k < DD; ++k) {
      float p = ps[k];
      o1 += p * g1_lW[(DD + k)*DD + d];
      o2 += p * g1_rW[(DD + k)*DD + d];
      o3 += p * g2_lW[(DD + k)*DD + d];
      o4 += p * g2_rW[(DD + k)*DD + d];
    }
    rT[(0*NR + blk)*DD + d] = o1;
    rT[(1*NR + blk)*DD + d] = o2;
    rT[(2*NR + blk)*DD + d] = o3;
    rT[(3*NR + blk)*DD + d] = o4;
  } else {
    const int b = blk - NR;
    for (int k = d; k < DIN; k += 64) { xs[k] = qh[b*DIN + k]; xs2[k] = qr[b*DIN + k]; }
    __syncthreads();
    float a = pb[d], a2 = pb[d];
    for (int k = 0; k < DIN; ++k) { a += xs[k]*pW[k*DD + d]; a2 += xs2[k]*pW[k*DD + d]; }
    ps[d] = tanhf(a); ps2[d] = tanhf(a2);
    __syncthreads();
    float o1 = g1_lb[d], o2 = g1_rb[d], o3 = g2_lb[d], o4 = g2_rb[d];
    for (int k = 0; k < DD; ++k) {
      float p = ps[k], p2 = ps2[k];
      o1 += p * g1_lW[(2*DD + k)*DD + d] + p2 * g1_lW[(3*DD + k)*DD + d];
      o2 += p * g1_rW[(2*DD + k)*DD + d] + p2 * g1_rW[(3*DD + k)*DD + d];
      o3 += p * g2_lW[(2*DD + k)*DD + d] + p2 * g2_lW[(3*DD + k)*DD + d];
      o4 += p * g2_rW[(2*DD + k)*DD + d] + p2 * g2_rW[(3*DD + k)*DD + d];
    }
    qT[(0*NB + b)*DD + d] = o1;
    qT[(1*NB + b)*DD + d] = o2;
    qT[(2*NB + b)*DD + d] = o3;
    qT[(3*NB + b)*DD + d] = o4;
  }
}

// persistent proj v6: 64-row tiles, COALESCED async staging via
// global_load_lds (dest linear row-major [64][104]; source pre-swizzled
// slot = k4 ^ ((row>>2)&7) so swizzled compute reads are conflict-free).
// Rounds 0/3/4 showed k_proj invariant to occupancy/barriers/FETCH and
// WORSE with extra VMEM (r4): the limiter is VMEM transaction rate from
// row-per-thread scattered staging (64 lines per wave-load). Coalesced
// staging cuts txns ~16x; async prefetch of tile t+1 issues before
// compute(t), drained by the ending barrier after a full compute phase.
// 4x4 register tile: acc16+xa16+w4 ~ 60 VGPR (no spill exposure).
__global__ __launch_bounds__(256, 2)
void k_proj(const float* __restrict__ hcon, const float* __restrict__ huncon,
            const float* __restrict__ pW, const float* __restrict__ pb,
            const int* __restrict__ lim, float* __restrict__ H) {
  __shared__ __align__(16) float pWs[DIN*DD];        // 25.6 KB
  __shared__ __align__(16) float Xb[2][PROJ_LDSF];   // 53.25 KB
  const int tid  = threadIdx.x;
  for (int i = tid; i < DIN*DD; i += 256) pWs[i] = pW[i];
  const int lane = tid & 63, wid = tid >> 6;
  const int tc = tid & 15, tr = tid >> 4;
  const int c0 = tc << 2, r0 = tr << 2;
  const float4 pbv = *(const float4*)&pb[c0];
  const int nmax = lim[1];
  const int tA = (nmax + 63) >> 6;
  const int tB = (NN + 63) >> 6;
  const int NT = tA + tB;
  const int key = tr & 7;   // == (row>>2)&7 for all 4 rows r0..r0+3

#define STAGE_TILE(T, BUF)                                                      \
  {                                                                             \
    const float* sbase; int rbase, rlim;                                        \
    if ((T) < tA) { sbase = hcon;   rbase = (T) << 6;        rlim = NM; }       \
    else          { sbase = huncon; rbase = ((T) - tA) << 6; rlim = NN; }       \
    _Pragma("unroll")                                                           \
    for (int j = 0; j < 7; ++j) {                                               \
      int ii = j*4 + wid;                                                       \
      if (ii < 26) {                                                            \
        int p16  = ii*64 + lane;                                                \
        int row  = p16 / 26;                                                    \
        int slot = p16 - row*26;                                                \
        int kk4  = (slot < 24) ? (slot ^ ((row >> 2) & 7)) : 24;                \
        int grow = rbase + row; if (grow >= rlim) grow = rlim - 1;              \
        const float* gp = sbase + (size_t)grow*DIN + kk4*4;                     \
        __builtin_amdgcn_global_load_lds(                                       \
            (const __attribute__((address_space(1))) void*)gp,                  \
            (__attribute__((address_space(3))) void*)(&Xb[(BUF)][0] + ii*256),  \
            16, 0, 0);                                                          \
      }                                                                         \
    }                                                                           \
  }

  {
    int t0 = blockIdx.x;
    if (t0 < NT) STAGE_TILE(t0, 0);
  }
  __syncthreads();   // pWs ready + first tile staged (vmcnt drained)

  int it = 0;
  for (int t = blockIdx.x; t < NT; t += gridDim.x, ++it) {
    const int buf = it & 1;
    const int tn = t + gridDim.x;
    if (tn < NT) STAGE_TILE(tn, buf ^ 1);   // async prefetch, no wait here

    float4 acc[4];
    #pragma unroll
    for (int i = 0; i < 4; ++i) acc[i] = make_float4(0.f, 0.f, 0.f, 0.f);

    const float* Xp = &Xb[buf][0];
    for (int k4 = 0; k4 < 25; ++k4) {
      const int slot = (k4 < 24) ? (k4 ^ key) : 24;
      float4 xa0 = *(const float4*)&Xp[(r0 + 0)*104 + slot*4];
      float4 xa1 = *(const float4*)&Xp[(r0 + 1)*104 + slot*4];
      float4 xa2 = *(const float4*)&Xp[(r0 + 2)*104 + slot*4];
      float4 xa3 = *(const float4*)&Xp[(r0 + 3)*104 + slot*4];
      const float* wb = &pWs[k4*4*DD + c0];
      {
        float4 w = *(const float4*)&wb[0*DD];
        fma4x4(make_float4(xa0.x, xa1.x, xa2.x, xa3.x), w, acc);
      }
      {
        float4 w = *(const float4*)&wb[1*DD];
        fma4x4(make_float4(xa0.y, xa1.y, xa2.y, xa3.y), w, acc);
      }
      {
        float4 w = *(const float4*)&wb[2*DD];
        fma4x4(make_float4(xa0.z, xa1.z, xa2.z, xa3.z), w, acc);
      }
      {
        float4 w = *(const float4*)&wb[3*DD];
        fma4x4(make_float4(xa0.w, xa1.w, xa2.w, xa3.w), w, acc);
      }
    }

    const int row0 = (t < tA) ? (t << 6) : (NM + ((t - tA) << 6));
    #pragma unroll
    for (int i = 0; i < 4; ++i) {
      int row = row0 + r0 + i;
      if (row < NH) {
        float4 o;
        o.x = tanhf(acc[i].x + pbv.x);
        o.y = tanhf(acc[i].y + pbv.y);
        o.z = tanhf(acc[i].z + pbv.z);
        o.w = tanhf(acc[i].w + pbv.w);
        *(float4*)&H[(size_t)row*DD + c0] = o;
      }
    }
    __syncthreads();   // all waves done reading buf; prefetch (issued pre-compute) drained
  }
#undef STAGE_TILE
}

// persistent transform, 256-row tiles, 8x8 register tile, weights resident.
// (round-3 version: the v5 prefetch variant spilled -- WRITE 580MB, VGPR 128)
// pool 0: rows<nvi : TA=H@W1a (in place), TA2=H@W2a
// pool 1: rows in [nvi,nmax): TA=H@W1b (in place)
// pool 2: huncon rows: HU2=H@g2_rW (in place)
__global__ __launch_bounds__(256, 2)
void k_tf(const float* __restrict__ g1_lW, const float* __restrict__ g1_rW,
          const float* __restrict__ g2_lW, const float* __restrict__ g2_rW,
          const int* __restrict__ lim,
          float* __restrict__ H, float* __restrict__ TA2) {
  __shared__ __align__(16) float Ws0[DD*DD];         // 16 KB
  __shared__ __align__(16) float Ws1[DD*DD];         // 16 KB
  __shared__ __align__(16) float Ht[32][XT_STRIDE];  // 33.3 KB
  const int tid = threadIdx.x;
  const int nvi  = lim[0];
  const int nmax = lim[1];
  int pool, pbase, pgrid;
  if (blockIdx.x < PA)           { pool = 0; pbase = blockIdx.x;           pgrid = PA; }
  else if (blockIdx.x < PA + PB) { pool = 1; pbase = blockIdx.x - PA;      pgrid = PB; }
  else                           { pool = 2; pbase = blockIdx.x - PA - PB; pgrid = PC; }
  if (pool == 0) {
    for (int i = tid; i < DD*DD; i += 256) { Ws0[i] = g1_lW[i]; Ws1[i] = g2_lW[i]; }
  } else if (pool == 1) {
    for (int i = tid; i < DD*DD; i += 256) Ws0[i] = g1_rW[i];
  } else {
    for (int i = tid; i < DD*DD; i += 256) Ws0[i] = g2_rW[i];
  }
  int t_begin, t_count, row_base;
  if (pool == 0)      { t_begin = 0;        t_count = (nvi + 255) >> 8;                 row_base = 0;  }
  else if (pool == 1) { t_begin = nvi >> 8; t_count = ((nmax + 255) >> 8) - (nvi >> 8); row_base = 0;  }
  else                { t_begin = 0;        t_count = (NN + 255) >> 8;                  row_base = NM; }
  const int tc = tid & 7, tr = tid >> 3;
  const int c0 = tc << 3;
  __syncthreads();
  for (int tt = pbase; tt < t_count; tt += pgrid) {
    const int row0 = row_base + ((t_begin + tt) << 8);
    const int myrow = row0 + tid;
    float4 a0[2][2][4], a1[2][2][4];
    #pragma unroll
    for (int a = 0; a < 2; ++a)
      #pragma unroll
      for (int b = 0; b < 2; ++b)
        #pragma unroll
        for (int i = 0; i < 4; ++i) {
          a0[a][b][i] = make_float4(0.f,0.f,0.f,0.f);
          a1[a][b][i] = make_float4(0.f,0.f,0.f,0.f);
        }
    #pragma unroll
    for (int chunk = 0; chunk < 2; ++chunk) {
      const int kb = chunk << 5;
      __syncthreads();
      if (myrow < NH) {
        const float* src = &H[(size_t)myrow*DD + kb];
        #pragma unroll
        for (int j = 0; j < 32; j += 4) {
          float4 v = *(const float4*)&src[j];
          Ht[j+0][tid] = v.x; Ht[j+1][tid] = v.y; Ht[j+2][tid] = v.z; Ht[j+3][tid] = v.w;
        }
      }
      __syncthreads();
      if (pool == 0) {
        for (int k = 0; k < 32; ++k) {
          float4 x0 = *(const float4*)&Ht[k][tr*8];
          float4 x1 = *(const float4*)&Ht[k][tr*8 + 4];
          float4 w0 = *(const float4*)&Ws0[(kb + k)*DD + c0];
          float4 w1 = *(const float4*)&Ws0[(kb + k)*DD + c0 + 4];
          float4 u0 = *(const float4*)&Ws1[(kb + k)*DD + c0];
          float4 u1 = *(const float4*)&Ws1[(kb + k)*DD + c0 + 4];
          fma4x4(x0, w0, a0[0][0]); fma4x4(x0, w1, a0[0][1]);
          fma4x4(x1, w0, a0[1][0]); fma4x4(x1, w1, a0[1][1]);
          fma4x4(x0, u0, a1[0][0]); fma4x4(x0, u1, a1[0][1]);
          fma4x4(x1, u0, a1[1][0]); fma4x4(x1, u1, a1[1][1]);
        }
      } else {
        for (int k = 0; k < 32; ++k) {
          float4 x0 = *(const float4*)&Ht[k][tr*8];
          float4 x1 = *(const float4*)&Ht[k][tr*8 + 4];
          float4 w0 = *(const float4*)&Ws0[(kb + k)*DD + c0];
          float4 w1 = *(const float4*)&Ws0[(kb + k)*DD + c0 + 4];
          fma4x4(x0, w0, a0[0][0]); fma4x4(x0, w1, a0[0][1]);
          fma4x4(x1, w0, a0[1][0]); fma4x4(x1, w1, a0[1][1]);
        }
      }
    }
    #pragma unroll
    for (int a = 0; a < 2; ++a)
      #pragma unroll
      for (int i = 0; i < 4; ++i) {
        int row = row0 + tr*8 + a*4 + i;
        bool ok;
        if (pool == 0)      ok = (row < nvi);
        else if (pool == 1) ok = (row >= nvi && row < nmax);
        else                ok = (row < NH);
        if (ok) {
          *(float4*)&H[row*DD + c0]     = a0[a][0][i];
          *(float4*)&H[row*DD + c0 + 4] = a0[a][1][i];
          if (pool == 0) {
            *(float4*)&TA2[row*DD + c0]     = a1[a][0][i];
            *(float4*)&TA2[row*DD + c0 + 4] = a1[a][1][i];
          }
        }
      }
  }
}

// persistent edge kernel: cW1/cW2 transposed + cb resident in LDS.
__global__ __launch_bounds__(256, 2)
void k_edges(const int* __restrict__ edges,
             const float* __restrict__ TA, const float* __restrict__ TA2,
             const float* __restrict__ HU2,
             const float* __restrict__ rT, const float* __restrict__ qT,
             const float* __restrict__ cW1, const float* __restrict__ cb1,
             const float* __restrict__ cW2, const float* __restrict__ cb2,
             float* __restrict__ logits) {
  __shared__ __align__(16) float Wt1s[DD*68];
  __shared__ __align__(16) float Wt2s[DD*68];
  __shared__ __align__(16) float Lt[DD][68];
  __shared__ __align__(16) float Rt[DD][68];
  __shared__ __align__(16) float4 cbs4[2][16];
  __shared__ float lg[64];
  __shared__ int   se[64*8];
  const int tid = threadIdx.x;
  for (int i = tid; i < DD*DD; i += 256) {
    int k = i >> 6, d = i & 63;
    Wt1s[d*68 + k] = cW1[i];   // Wt[d][k] = cW[k][d]
    Wt2s[d*68 + k] = cW2[i];
  }
  if (tid < 16) {
    cbs4[0][tid] = *(const float4*)&cb1[tid*4];
    cbs4[1][tid] = *(const float4*)&cb2[tid*4];
  }
  const int e   = tid >> 2;
  const int d0  = (tid & 3) * 16;
  const int ee0 = (tid & 15) << 2;
  const int k0  = (tid >> 4) << 2;
  __syncthreads();
  const int NT = (NE + 63) / 64;
  for (int tile = blockIdx.x; tile < NT; tile += gridDim.x) {
    const int e0 = tile * 64;
    const int ecnt = min(64, NE - e0);
    for (int i = tid; i < 64*8; i += 256) se[i] = (i < ecnt*8) ? edges[e0*8 + i] : 0;
    if (tid < 64) lg[tid] = 0.f;
    __syncthreads();
    const int rel = se[e*8 + 3];
    const int eg  = se[e*8 + 0];
    const int li  = se[e*8 + 6];
    for (int g = 0; g < 2; ++g) {
      const float* Lb = g ? TA2 : TA;
      const float* Rb = g ? HU2 : TA;
      const float* rL = rT + (g ? 2*NR*DD : 0);
      const float* rR = rT + (g ? 3*NR*DD : 1*NR*DD);
      const float* qL = qT + (g ? 2*NB*DD : 0);
      const float* qR = qT + (g ? 3*NB*DD : 1*NB*DD);
      const float* Wts = g ? Wt2s : Wt1s;
      const int ri = g ? se[e*8 + 2] : se[e*8 + 7];
      float cbp = 0.f;
      #pragma unroll
      for (int di = 0; di < 4; ++di) {
        const int d = d0 + 4*di;
        float4 l = *(const float4*)&Lb[li*DD + d];
        float4 t = *(const float4*)&rL[rel*DD + d];
        float4 u = *(const float4*)&qL[eg*DD + d];
        l.x += t.x + u.x; l.y += t.y + u.y; l.z += t.z + u.z; l.w += t.w + u.w;
        l = leaky4(l);
        Lt[d+0][e] = l.x; Lt[d+1][e] = l.y; Lt[d+2][e] = l.z; Lt[d+3][e] = l.w;
        float4 c = cbs4[g][d >> 2];
        cbp += l.x*c.x + l.y*c.y + l.z*c.z + l.w*c.w;
        float4 r = *(const float4*)&Rb[ri*DD + d];
        t = *(const float4*)&rR[rel*DD + d];
        u = *(const float4*)&qR[eg*DD + d];
        r.x += t.x + u.x; r.y += t.y + u.y; r.z += t.z + u.z; r.w += t.w + u.w;
        r = leaky4(r);
        Rt[d+0][e] = r.x; Rt[d+1][e] = r.y; Rt[d+2][e] = r.z; Rt[d+3][e] = r.w;
      }
      atomicAdd(&lg[e], cbp);
      __syncthreads();
      float4 z[4] = {{0,0,0,0},{0,0,0,0},{0,0,0,0},{0,0,0,0}};
      for (int d = 0; d < DD; ++d) {
        float4 x = *(const float4*)&Lt[d][ee0];
        float4 w = *(const float4*)&Wts[d*68 + k0];
        fma4x4(x, w, z);
      }
      {
        float4 r0v = *(const float4*)&Rt[k0+0][ee0];
        float4 r1v = *(const float4*)&Rt[k0+1][ee0];
        float4 r2v = *(const float4*)&Rt[k0+2][ee0];
        float4 r3v = *(const float4*)&Rt[k0+3][ee0];
        float p0 = z[0].x*r0v.x + z[0].y*r1v.x + z[0].z*r2v.x + z[0].w*r3v.x;
        float p1 = z[1].x*r0v.y + z[1].y*r1v.y + z[1].z*r2v.y + z[1].w*r3v.y;
        float p2 = z[2].x*r0v.z + z[2].y*r1v.z + z[2].z*r2v.z + z[2].w*r3v.z;
        float p3 = z[3].x*r0v.w + z[3].y*r1v.w + z[3].z*r2v.w + z[3].w*r3v.w;
        atomicAdd(&lg[ee0+0], p0);
        atomicAdd(&lg[ee0+1], p1);
        atomicAdd(&lg[ee0+2], p2);
        atomicAdd(&lg[ee0+3], p3);
      }
      __syncthreads();
    }
    if (tid < ecnt) logits[e0 + tid] = lg[tid];
    __syncthreads();
  }
}

__global__ void k_softmax(const int* __restrict__ edges, const float* __restrict__ logits,
                          const float* __restrict__ na, float* __restrict__ out) {
  int e = blockIdx.x * blockDim.x + threadIdx.x;
  if (e >= NE) return;
  int seg = edges[e*8 + 4];
  if (e > 0 && edges[(e-1)*8 + 4] == seg) return;  // not a segment head
  int j = e;
  float m = -1e30f;
  while (j < NE && edges[j*8 + 4] == seg) { m = fmaxf(m, logits[j]); ++j; }
  float s = 0.f;
  for (int t = e; t < j; ++t) s += expf(logits[t] - m);
  int eg = edges[e*8 + 0], vi = edges[e*8 + 1];
  float scale = na[eg*NN + vi] / s;
  for (int t = e; t < j; ++t) {
    int vj = edges[t*8 + 2];
    __hip_atomic_fetch_add(&out[eg*NN + vj], expf(logits[t] - m) * scale,
                           __ATOMIC_RELAXED, __HIP_MEMORY_SCOPE_AGENT);
  }
}

__global__ void k_rowsum(const float* __restrict__ out, float* __restrict__ bsum) {
  int b = blockIdx.y;
  float s = 0.f;
  for (int n = blockIdx.x * blockDim.x + threadIdx.x; n < NN; n += gridDim.x * blockDim.x)
    s += out[b*NN + n];
  for (int off = 32; off > 0; off >>= 1) s += __shfl_down(s, off);
  if ((threadIdx.x & 63) == 0)
    __hip_atomic_fetch_add(&bsum[b], s, __ATOMIC_RELAXED, __HIP_MEMORY_SCOPE_AGENT);
}

__global__ void k_div(float* __restrict__ out, const float* __restrict__ bsum) {
  int i = blockIdx.x * blockDim.x + threadIdx.x;
  if (i < NB*NN) out[i] /= bsum[i / NN];
}

extern "C" void kernel_launch(void* const* d_in, const int* in_sizes, int n_in,
                              void* d_out, int out_size, void* d_ws, size_t ws_size,
                              hipStream_t stream) {
  (void)in_sizes; (void)n_in; (void)out_size; (void)ws_size;
  const float* na     = (const float*)d_in[0];
  const int*   edges  = (const int*)  d_in[1];
  const float* huncon = (const float*)d_in[2];
  const float* hcon   = (const float*)d_in[3];
  const float* rtab   = (const float*)d_in[4];
  const float* qh     = (const float*)d_in[5];
  const float* qr     = (const float*)d_in[6];
  const float* pW     = (const float*)d_in[7];
  const float* pb     = (const float*)d_in[8];
  const float* g1_lW  = (const float*)d_in[9];
  const float* g1_lb  = (const float*)d_in[10];
  const float* g1_rW  = (const float*)d_in[11];
  const float* g1_rb  = (const float*)d_in[12];
  const float* g1_cW  = (const float*)d_in[13];
  const float* g1_cb  = (const float*)d_in[14];
  const float* g2_lW  = (const float*)d_in[15];
  const float* g2_lb  = (const float*)d_in[16];
  const float* g2_rW  = (const float*)d_in[17];
  const float* g2_rb  = (const float*)d_in[18];
  const float* g2_cW  = (const float*)d_in[19];
  const float* g2_cb  = (const float*)d_in[20];
  float* out  = (float*)d_out;
  float* ws   = (float*)d_ws;
  int*   wsI  = (int*)d_ws;
  float* bsum = ws + 16;
  float* H    = ws + H_OFF;            // TA in-place; HU2 = H + NM*DD
  float* TA2  = ws + TA2_OFF;
  float* rT   = ws + RT_OFF;
  float* qT   = ws + QT_OFF;
  float* lgp  = ws + LG_OFF;

  hipMemsetAsync(d_out, 0, (size_t)NB*NN*sizeof(float), stream);
  k_init<<<1, 64, 0, stream>>>(wsI, bsum);
  k_limits<<<(NE + 255)/256, 256, 0, stream>>>(edges, wsI);
  k_tables<<<NR + NB, 64, 0, stream>>>(rtab, qh, qr, pW, pb,
                                       g1_lW, g1_lb, g1_rW, g1_rb,
                                       g2_lW, g2_lb, g2_rW, g2_rb, rT, qT);
  k_proj<<<768, 256, 0, stream>>>(hcon, huncon, pW, pb, wsI, H);
  k_tf<<<PA + PB + PC, 256, 0, stream>>>(g1_lW, g1_rW, g2_lW, g2_rW, wsI, H, TA2);
  k_edges<<<512, 256, 0, stream>>>(edges, H, TA2, H + NM*DD, rT, qT,
                                   g1_cW, g1_cb, g2_cW, g2_cb, lgp);
  k_softmax<<<(NE + 255)/256, 256, 0, stream>>>(edges, lgp, na, out);
  k_rowsum<<<dim3(32, 16), 256, 0, stream>>>(out, bsum);
  k_div<<<(NB*NN + 255)/256, 256, 0, stream>>>(out, bsum);
}

// Round 7
// 796.386 us; speedup vs baseline: 1.2048x; 1.0142x over previous
//
#include <hip/hip_runtime.h>

#define DIN 100
#define DD  64
#define NE  250000
#define NB  16
#define NN  50000
#define NR  500
#define NM  500000
#define NH  (NM + NN)

// workspace layout (float offsets). H doubles as TA (rows<nmax, in-place)
// and HU2 (rows >= NM, in-place).
#define H_OFF    64
#define TA2_OFF  (H_OFF + NH*DD)
#define RT_OFF   (TA2_OFF + NE*DD)
#define QT_OFF   (RT_OFF + 4*NR*DD)
#define LG_OFF   (QT_OFF + 4*NB*DD)

// k_tf grid segmentation (pool0 does 2 GEMMs -> 2:1:~1/6 work split)
#define PA 320
#define PB 160
#define PC 32

#define XT_STRIDE 260   // %32==4 -> 2-way (free) on tiled reads; 16B-aligned rows

// k_proj v6: 64-row tiles, row-major LDS (104-float padded rows), XOR-swizzled
#define PROJ_LDSF (64*104)    // floats per staging buffer (26.62 KB)

__device__ __forceinline__ void fma4x4(const float4 x, const float4 w, float4 acc[4]) {
  acc[0].x += x.x*w.x; acc[0].y += x.x*w.y; acc[0].z += x.x*w.z; acc[0].w += x.x*w.w;
  acc[1].x += x.y*w.x; acc[1].y += x.y*w.y; acc[1].z += x.y*w.z; acc[1].w += x.y*w.w;
  acc[2].x += x.z*w.x; acc[2].y += x.z*w.y; acc[2].z += x.z*w.z; acc[2].w += x.z*w.w;
  acc[3].x += x.w*w.x; acc[3].y += x.w*w.y; acc[3].z += x.w*w.z; acc[3].w += x.w*w.w;
}

__device__ __forceinline__ float4 leaky4(float4 v) {
  v.x = v.x > 0.f ? v.x : 0.2f*v.x;
  v.y = v.y > 0.f ? v.y : 0.2f*v.y;
  v.z = v.z > 0.f ? v.z : 0.2f*v.z;
  v.w = v.w > 0.f ? v.w : 0.2f*v.w;
  return v;
}

__global__ void k_init(int* wsI, float* bsum) {
  if (threadIdx.x == 0) { wsI[0] = 0x7fffffff; wsI[1] = 0; }
  if (threadIdx.x < NB) bsum[threadIdx.x] = 0.f;
}

__global__ void k_limits(const int* __restrict__ edges, int* __restrict__ wsI) {
  int i = blockIdx.x * blockDim.x + threadIdx.x;
  int mn = 0x7fffffff, mx = -1;
  if (i < NE) { int v = edges[i*8 + 7]; mn = v; mx = v; }
  for (int off = 32; off > 0; off >>= 1) {
    mn = min(mn, __shfl_down(mn, off));
    mx = max(mx, __shfl_down(mx, off));
  }
  if ((threadIdx.x & 63) == 0) {
    atomicMin(&wsI[0], mn);
    atomicMax(&wsI[1], mx + 1);
  }
}

// one 64-thread block per (rel row | batch row): builds per-rel / per-batch tables
__global__ void k_tables(const float* __restrict__ rtab,
                         const float* __restrict__ qh, const float* __restrict__ qr,
                         const float* __restrict__ pW, const float* __restrict__ pb,
                         const float* __restrict__ g1_lW, const float* __restrict__ g1_lb,
                         const float* __restrict__ g1_rW, const float* __restrict__ g1_rb,
                         const float* __restrict__ g2_lW, const float* __restrict__ g2_lb,
                         const float* __restrict__ g2_rW, const float* __restrict__ g2_rb,
                         float* __restrict__ rT, float* __restrict__ qT) {
  __shared__ float xs[DIN], xs2[DIN], ps[DD], ps2[DD];
  const int d = threadIdx.x;
  const int blk = blockIdx.x;
  if (blk < NR) {
    for (int k = d; k < DIN; k += 64) xs[k] = rtab[blk*DIN + k];
    __syncthreads();
    float a = pb[d];
    for (int k = 0; k < DIN; ++k) a += xs[k] * pW[k*DD + d];
    ps[d] = tanhf(a);
    __syncthreads();
    float o1 = 0.f, o2 = 0.f, o3 = 0.f, o4 = 0.f;
    for (int k = 0; k < DD; ++k) {
      float p = ps[k];
      o1 += p * g1_lW[(DD + k)*DD + d];
      o2 += p * g1_rW[(DD + k)*DD + d];
      o3 += p * g2_lW[(DD + k)*DD + d];
      o4 += p * g2_rW[(DD + k)*DD + d];
    }
    rT[(0*NR + blk)*DD + d] = o1;
    rT[(1*NR + blk)*DD + d] = o2;
    rT[(2*NR + blk)*DD + d] = o3;
    rT[(3*NR + blk)*DD + d] = o4;
  } else {
    const int b = blk - NR;
    for (int k = d; k < DIN; k += 64) { xs[k] = qh[b*DIN + k]; xs2[k] = qr[b*DIN + k]; }
    __syncthreads();
    float a = pb[d], a2 = pb[d];
    for (int k = 0; k < DIN; ++k) { a += xs[k]*pW[k*DD + d]; a2 += xs2[k]*pW[k*DD + d]; }
    ps[d] = tanhf(a); ps2[d] = tanhf(a2);
    __syncthreads();
    float o1 = g1_lb[d], o2 = g1_rb[d], o3 = g2_lb[d], o4 = g2_rb[d];
    for (int k = 0; k < DD; ++k) {
      float p = ps[k], p2 = ps2[k];
      o1 += p * g1_lW[(2*DD + k)*DD + d] + p2 * g1_lW[(3*DD + k)*DD + d];
      o2 += p * g1_rW[(2*DD + k)*DD + d] + p2 * g1_rW[(3*DD + k)*DD + d];
      o3 += p * g2_lW[(2*DD + k)*DD + d] + p2 * g2_lW[(3*DD + k)*DD + d];
      o4 += p * g2_rW[(2*DD + k)*DD + d] + p2 * g2_rW[(3*DD + k)*DD + d];
    }
    qT[(0*NB + b)*DD + d] = o1;
    qT[(1*NB + b)*DD + d] = o2;
    qT[(2*NB + b)*DD + d] = o3;
    qT[(3*NB + b)*DD + d] = o4;
  }
}

// persistent proj v6 (frozen): coalesced async staging via global_load_lds,
// XOR-swizzled slots, 4x4 register tile. ~173us across 4 staging schemes ->
// near the structure's issue-rate plateau; see round-6 postmortem.
__global__ __launch_bounds__(256, 2)
void k_proj(const float* __restrict__ hcon, const float* __restrict__ huncon,
            const float* __restrict__ pW, const float* __restrict__ pb,
            const int* __restrict__ lim, float* __restrict__ H) {
  __shared__ __align__(16) float pWs[DIN*DD];        // 25.6 KB
  __shared__ __align__(16) float Xb[2][PROJ_LDSF];   // 53.25 KB
  const int tid  = threadIdx.x;
  for (int i = tid; i < DIN*DD; i += 256) pWs[i] = pW[i];
  const int lane = tid & 63, wid = tid >> 6;
  const int tc = tid & 15, tr = tid >> 4;
  const int c0 = tc << 2, r0 = tr << 2;
  const float4 pbv = *(const float4*)&pb[c0];
  const int nmax = lim[1];
  const int tA = (nmax + 63) >> 6;
  const int tB = (NN + 63) >> 6;
  const int NT = tA + tB;
  const int key = tr & 7;   // == (row>>2)&7 for all 4 rows r0..r0+3

#define STAGE_TILE(T, BUF)                                                      \
  {                                                                             \
    const float* sbase; int rbase, rlim;                                        \
    if ((T) < tA) { sbase = hcon;   rbase = (T) << 6;        rlim = NM; }       \
    else          { sbase = huncon; rbase = ((T) - tA) << 6; rlim = NN; }       \
    _Pragma("unroll")                                                           \
    for (int j = 0; j < 7; ++j) {                                               \
      int ii = j*4 + wid;                                                       \
      if (ii < 26) {                                                            \
        int p16  = ii*64 + lane;                                                \
        int row  = p16 / 26;                                                    \
        int slot = p16 - row*26;                                                \
        int kk4  = (slot < 24) ? (slot ^ ((row >> 2) & 7)) : 24;                \
        int grow = rbase + row; if (grow >= rlim) grow = rlim - 1;              \
        const float* gp = sbase + (size_t)grow*DIN + kk4*4;                     \
        __builtin_amdgcn_global_load_lds(                                       \
            (const __attribute__((address_space(1))) void*)gp,                  \
            (__attribute__((address_space(3))) void*)(&Xb[(BUF)][0] + ii*256),  \
            16, 0, 0);                                                          \
      }                                                                         \
    }                                                                           \
  }

  {
    int t0 = blockIdx.x;
    if (t0 < NT) STAGE_TILE(t0, 0);
  }
  __syncthreads();   // pWs ready + first tile staged (vmcnt drained)

  int it = 0;
  for (int t = blockIdx.x; t < NT; t += gridDim.x, ++it) {
    const int buf = it & 1;
    const int tn = t + gridDim.x;
    if (tn < NT) STAGE_TILE(tn, buf ^ 1);   // async prefetch, no wait here

    float4 acc[4];
    #pragma unroll
    for (int i = 0; i < 4; ++i) acc[i] = make_float4(0.f, 0.f, 0.f, 0.f);

    const float* Xp = &Xb[buf][0];
    for (int k4 = 0; k4 < 25; ++k4) {
      const int slot = (k4 < 24) ? (k4 ^ key) : 24;
      float4 xa0 = *(const float4*)&Xp[(r0 + 0)*104 + slot*4];
      float4 xa1 = *(const float4*)&Xp[(r0 + 1)*104 + slot*4];
      float4 xa2 = *(const float4*)&Xp[(r0 + 2)*104 + slot*4];
      float4 xa3 = *(const float4*)&Xp[(r0 + 3)*104 + slot*4];
      const float* wb = &pWs[k4*4*DD + c0];
      {
        float4 w = *(const float4*)&wb[0*DD];
        fma4x4(make_float4(xa0.x, xa1.x, xa2.x, xa3.x), w, acc);
      }
      {
        float4 w = *(const float4*)&wb[1*DD];
        fma4x4(make_float4(xa0.y, xa1.y, xa2.y, xa3.y), w, acc);
      }
      {
        float4 w = *(const float4*)&wb[2*DD];
        fma4x4(make_float4(xa0.z, xa1.z, xa2.z, xa3.z), w, acc);
      }
      {
        float4 w = *(const float4*)&wb[3*DD];
        fma4x4(make_float4(xa0.w, xa1.w, xa2.w, xa3.w), w, acc);
      }
    }

    const int row0 = (t < tA) ? (t << 6) : (NM + ((t - tA) << 6));
    #pragma unroll
    for (int i = 0; i < 4; ++i) {
      int row = row0 + r0 + i;
      if (row < NH) {
        float4 o;
        o.x = tanhf(acc[i].x + pbv.x);
        o.y = tanhf(acc[i].y + pbv.y);
        o.z = tanhf(acc[i].z + pbv.z);
        o.w = tanhf(acc[i].w + pbv.w);
        *(float4*)&H[(size_t)row*DD + c0] = o;
      }
    }
    __syncthreads();   // all waves done reading buf; prefetch (issued pre-compute) drained
  }
#undef STAGE_TILE
}

// persistent transform, 256-row tiles, 8x8 register tile, weights resident.
// (round-3 version; v5 prefetch variant spilled)
__global__ __launch_bounds__(256, 2)
void k_tf(const float* __restrict__ g1_lW, const float* __restrict__ g1_rW,
          const float* __restrict__ g2_lW, const float* __restrict__ g2_rW,
          const int* __restrict__ lim,
          float* __restrict__ H, float* __restrict__ TA2) {
  __shared__ __align__(16) float Ws0[DD*DD];         // 16 KB
  __shared__ __align__(16) float Ws1[DD*DD];         // 16 KB
  __shared__ __align__(16) float Ht[32][XT_STRIDE];  // 33.3 KB
  const int tid = threadIdx.x;
  const int nvi  = lim[0];
  const int nmax = lim[1];
  int pool, pbase, pgrid;
  if (blockIdx.x < PA)           { pool = 0; pbase = blockIdx.x;           pgrid = PA; }
  else if (blockIdx.x < PA + PB) { pool = 1; pbase = blockIdx.x - PA;      pgrid = PB; }
  else                           { pool = 2; pbase = blockIdx.x - PA - PB; pgrid = PC; }
  if (pool == 0) {
    for (int i = tid; i < DD*DD; i += 256) { Ws0[i] = g1_lW[i]; Ws1[i] = g2_lW[i]; }
  } else if (pool == 1) {
    for (int i = tid; i < DD*DD; i += 256) Ws0[i] = g1_rW[i];
  } else {
    for (int i = tid; i < DD*DD; i += 256) Ws0[i] = g2_rW[i];
  }
  int t_begin, t_count, row_base;
  if (pool == 0)      { t_begin = 0;        t_count = (nvi + 255) >> 8;                 row_base = 0;  }
  else if (pool == 1) { t_begin = nvi >> 8; t_count = ((nmax + 255) >> 8) - (nvi >> 8); row_base = 0;  }
  else                { t_begin = 0;        t_count = (NN + 255) >> 8;                  row_base = NM; }
  const int tc = tid & 7, tr = tid >> 3;
  const int c0 = tc << 3;
  __syncthreads();
  for (int tt = pbase; tt < t_count; tt += pgrid) {
    const int row0 = row_base + ((t_begin + tt) << 8);
    const int myrow = row0 + tid;
    float4 a0[2][2][4], a1[2][2][4];
    #pragma unroll
    for (int a = 0; a < 2; ++a)
      #pragma unroll
      for (int b = 0; b < 2; ++b)
        #pragma unroll
        for (int i = 0; i < 4; ++i) {
          a0[a][b][i] = make_float4(0.f,0.f,0.f,0.f);
          a1[a][b][i] = make_float4(0.f,0.f,0.f,0.f);
        }
    #pragma unroll
    for (int chunk = 0; chunk < 2; ++chunk) {
      const int kb = chunk << 5;
      __syncthreads();
      if (myrow < NH) {
        const float* src = &H[(size_t)myrow*DD + kb];
        #pragma unroll
        for (int j = 0; j < 32; j += 4) {
          float4 v = *(const float4*)&src[j];
          Ht[j+0][tid] = v.x; Ht[j+1][tid] = v.y; Ht[j+2][tid] = v.z; Ht[j+3][tid] = v.w;
        }
      }
      __syncthreads();
      if (pool == 0) {
        for (int k = 0; k < 32; ++k) {
          float4 x0 = *(const float4*)&Ht[k][tr*8];
          float4 x1 = *(const float4*)&Ht[k][tr*8 + 4];
          float4 w0 = *(const float4*)&Ws0[(kb + k)*DD + c0];
          float4 w1 = *(const float4*)&Ws0[(kb + k)*DD + c0 + 4];
          float4 u0 = *(const float4*)&Ws1[(kb + k)*DD + c0];
          float4 u1 = *(const float4*)&Ws1[(kb + k)*DD + c0 + 4];
          fma4x4(x0, w0, a0[0][0]); fma4x4(x0, w1, a0[0][1]);
          fma4x4(x1, w0, a0[1][0]); fma4x4(x1, w1, a0[1][1]);
          fma4x4(x0, u0, a1[0][0]); fma4x4(x0, u1, a1[0][1]);
          fma4x4(x1, u0, a1[1][0]); fma4x4(x1, u1, a1[1][1]);
        }
      } else {
        for (int k = 0; k < 32; ++k) {
          float4 x0 = *(const float4*)&Ht[k][tr*8];
          float4 x1 = *(const float4*)&Ht[k][tr*8 + 4];
          float4 w0 = *(const float4*)&Ws0[(kb + k)*DD + c0];
          float4 w1 = *(const float4*)&Ws0[(kb + k)*DD + c0 + 4];
          fma4x4(x0, w0, a0[0][0]); fma4x4(x0, w1, a0[0][1]);
          fma4x4(x1, w0, a0[1][0]); fma4x4(x1, w1, a0[1][1]);
        }
      }
    }
    #pragma unroll
    for (int a = 0; a < 2; ++a)
      #pragma unroll
      for (int i = 0; i < 4; ++i) {
        int row = row0 + tr*8 + a*4 + i;
        bool ok;
        if (pool == 0)      ok = (row < nvi);
        else if (pool == 1) ok = (row >= nvi && row < nmax);
        else                ok = (row < NH);
        if (ok) {
          *(float4*)&H[row*DD + c0]     = a0[a][0][i];
          *(float4*)&H[row*DD + c0 + 4] = a0[a][1][i];
          if (pool == 0) {
            *(float4*)&TA2[row*DD + c0]     = a1[a][0][i];
            *(float4*)&TA2[row*DD + c0 + 4] = a1[a][1][i];
          }
        }
      }
  }
}

// persistent edge kernel v2: cW read from GLOBAL in natural layout via
// operand swap (GEMM over Rt with cW[a][b] rows; final dot with Lt) --
// bilinear form sum_{a,b} r_a cW[a,b] l_b is order-agnostic. Drops the
// 34.8KB transposed-weight LDS -> 38KB total -> 4 blocks/CU (was 2):
// doubles waves hiding the random TA/TA2/HU2 row-gather latency that
// had this kernel at 9% HBM / 25% VALU / 20% occupancy.
__global__ __launch_bounds__(256, 2)
void k_edges(const int* __restrict__ edges,
             const float* __restrict__ TA, const float* __restrict__ TA2,
             const float* __restrict__ HU2,
             const float* __restrict__ rT, const float* __restrict__ qT,
             const float* __restrict__ cW1, const float* __restrict__ cb1,
             const float* __restrict__ cW2, const float* __restrict__ cb2,
             float* __restrict__ logits) {
  __shared__ __align__(16) float Lt[DD][68];
  __shared__ __align__(16) float Rt[DD][68];
  __shared__ __align__(16) float4 cbs4[2][16];
  __shared__ float lg[64];
  __shared__ int   se[64*8];
  const int tid = threadIdx.x;
  if (tid < 16) {
    cbs4[0][tid] = *(const float4*)&cb1[tid*4];
    cbs4[1][tid] = *(const float4*)&cb2[tid*4];
  }
  const int e   = tid >> 2;
  const int d0  = (tid & 3) * 16;
  const int ee0 = (tid & 15) << 2;
  const int b0  = (tid >> 4) << 2;
  __syncthreads();
  const int NT = (NE + 63) / 64;
  for (int tile = blockIdx.x; tile < NT; tile += gridDim.x) {
    const int e0 = tile * 64;
    const int ecnt = min(64, NE - e0);
    for (int i = tid; i < 64*8; i += 256) se[i] = (i < ecnt*8) ? edges[e0*8 + i] : 0;
    if (tid < 64) lg[tid] = 0.f;
    __syncthreads();
    const int rel = se[e*8 + 3];
    const int eg  = se[e*8 + 0];
    const int li  = se[e*8 + 6];
    for (int g = 0; g < 2; ++g) {
      const float* Lb = g ? TA2 : TA;
      const float* Rb = g ? HU2 : TA;
      const float* rL = rT + (g ? 2*NR*DD : 0);
      const float* rR = rT + (g ? 3*NR*DD : 1*NR*DD);
      const float* qL = qT + (g ? 2*NB*DD : 0);
      const float* qR = qT + (g ? 3*NB*DD : 1*NB*DD);
      const float* cWg = g ? cW2 : cW1;
      const int ri = g ? se[e*8 + 2] : se[e*8 + 7];
      float cbp = 0.f;
      #pragma unroll
      for (int di = 0; di < 4; ++di) {
        const int d = d0 + 4*di;
        float4 l = *(const float4*)&Lb[li*DD + d];
        float4 t = *(const float4*)&rL[rel*DD + d];
        float4 u = *(const float4*)&qL[eg*DD + d];
        l.x += t.x + u.x; l.y += t.y + u.y; l.z += t.z + u.z; l.w += t.w + u.w;
        l = leaky4(l);
        Lt[d+0][e] = l.x; Lt[d+1][e] = l.y; Lt[d+2][e] = l.z; Lt[d+3][e] = l.w;
        float4 c = cbs4[g][d >> 2];
        cbp += l.x*c.x + l.y*c.y + l.z*c.z + l.w*c.w;
        float4 r = *(const float4*)&Rb[ri*DD + d];
        t = *(const float4*)&rR[rel*DD + d];
        u = *(const float4*)&qR[eg*DD + d];
        r.x += t.x + u.x; r.y += t.y + u.y; r.z += t.z + u.z; r.w += t.w + u.w;
        r = leaky4(r);
        Rt[d+0][e] = r.x; Rt[d+1][e] = r.y; Rt[d+2][e] = r.z; Rt[d+3][e] = r.w;
      }
      atomicAdd(&lg[e], cbp);
      __syncthreads();
      // z[b0..b0+3] per edge = sum_a Rt[a][e] * cW[a*64 + b0..b0+3]
      float4 z[4] = {{0,0,0,0},{0,0,0,0},{0,0,0,0},{0,0,0,0}};
      #pragma unroll 8
      for (int a = 0; a < DD; ++a) {
        float4 x = *(const float4*)&Rt[a][ee0];
        float4 w = *(const float4*)&cWg[a*DD + b0];
        fma4x4(x, w, z);
      }
      {
        // p_i = sum_b z[i].b * Lt[b][edge_i]
        float4 l0v = *(const float4*)&Lt[b0+0][ee0];
        float4 l1v = *(const float4*)&Lt[b0+1][ee0];
        float4 l2v = *(const float4*)&Lt[b0+2][ee0];
        float4 l3v = *(const float4*)&Lt[b0+3][ee0];
        float p0 = z[0].x*l0v.x + z[0].y*l1v.x + z[0].z*l2v.x + z[0].w*l3v.x;
        float p1 = z[1].x*l0v.y + z[1].y*l1v.y + z[1].z*l2v.y + z[1].w*l3v.y;
        float p2 = z[2].x*l0v.z + z[2].y*l1v.z + z[2].z*l2v.z + z[2].w*l3v.z;
        float p3 = z[3].x*l0v.w + z[3].y*l1v.w + z[3].z*l2v.w + z[3].w*l3v.w;
        atomicAdd(&lg[ee0+0], p0);
        atomicAdd(&lg[ee0+1], p1);
        atomicAdd(&lg[ee0+2], p2);
        atomicAdd(&lg[ee0+3], p3);
      }
      __syncthreads();
    }
    if (tid < ecnt) logits[e0 + tid] = lg[tid];
    __syncthreads();
  }
}

__global__ void k_softmax(const int* __restrict__ edges, const float* __restrict__ logits,
                          const float* __restrict__ na, float* __restrict__ out) {
  int e = blockIdx.x * blockDim.x + threadIdx.x;
  if (e >= NE) return;
  int seg = edges[e*8 + 4];
  if (e > 0 && edges[(e-1)*8 + 4] == seg) return;  // not a segment head
  int j = e;
  float m = -1e30f;
  while (j < NE && edges[j*8 + 4] == seg) { m = fmaxf(m, logits[j]); ++j; }
  float s = 0.f;
  for (int t = e; t < j; ++t) s += expf(logits[t] - m);
  int eg = edges[e*8 + 0], vi = edges[e*8 + 1];
  float scale = na[eg*NN + vi] / s;
  for (int t = e; t < j; ++t) {
    int vj = edges[t*8 + 2];
    __hip_atomic_fetch_add(&out[eg*NN + vj], expf(logits[t] - m) * scale,
                           __ATOMIC_RELAXED, __HIP_MEMORY_SCOPE_AGENT);
  }
}

__global__ void k_rowsum(const float* __restrict__ out, float* __restrict__ bsum) {
  int b = blockIdx.y;
  float s = 0.f;
  for (int n = blockIdx.x * blockDim.x + threadIdx.x; n < NN; n += gridDim.x * blockDim.x)
    s += out[b*NN + n];
  for (int off = 32; off > 0; off >>= 1) s += __shfl_down(s, off);
  if ((threadIdx.x & 63) == 0)
    __hip_atomic_fetch_add(&bsum[b], s, __ATOMIC_RELAXED, __HIP_MEMORY_SCOPE_AGENT);
}

__global__ void k_div(float* __restrict__ out, const float* __restrict__ bsum) {
  int i = blockIdx.x * blockDim.x + threadIdx.x;
  if (i < NB*NN) out[i] /= bsum[i / NN];
}

extern "C" void kernel_launch(void* const* d_in, const int* in_sizes, int n_in,
                              void* d_out, int out_size, void* d_ws, size_t ws_size,
                              hipStream_t stream) {
  (void)in_sizes; (void)n_in; (void)out_size; (void)ws_size;
  const float* na     = (const float*)d_in[0];
  const int*   edges  = (const int*)  d_in[1];
  const float* huncon = (const float*)d_in[2];
  const float* hcon   = (const float*)d_in[3];
  const float* rtab   = (const float*)d_in[4];
  const float* qh     = (const float*)d_in[5];
  const float* qr     = (const float*)d_in[6];
  const float* pW     = (const float*)d_in[7];
  const float* pb     = (const float*)d_in[8];
  const float* g1_lW  = (const float*)d_in[9];
  const float* g1_lb  = (const float*)d_in[10];
  const float* g1_rW  = (const float*)d_in[11];
  const float* g1_rb  = (const float*)d_in[12];
  const float* g1_cW  = (const float*)d_in[13];
  const float* g1_cb  = (const float*)d_in[14];
  const float* g2_lW  = (const float*)d_in[15];
  const float* g2_lb  = (const float*)d_in[16];
  const float* g2_rW  = (const float*)d_in[17];
  const float* g2_rb  = (const float*)d_in[18];
  const float* g2_cW  = (const float*)d_in[19];
  const float* g2_cb  = (const float*)d_in[20];
  float* out  = (float*)d_out;
  float* ws   = (float*)d_ws;
  int*   wsI  = (int*)d_ws;
  float* bsum = ws + 16;
  float* H    = ws + H_OFF;            // TA in-place; HU2 = H + NM*DD
  float* TA2  = ws + TA2_OFF;
  float* rT   = ws + RT_OFF;
  float* qT   = ws + QT_OFF;
  float* lgp  = ws + LG_OFF;

  hipMemsetAsync(d_out, 0, (size_t)NB*NN*sizeof(float), stream);
  k_init<<<1, 64, 0, stream>>>(wsI, bsum);
  k_limits<<<(NE + 255)/256, 256, 0, stream>>>(edges, wsI);
  k_tables<<<NR + NB, 64, 0, stream>>>(rtab, qh, qr, pW, pb,
                                       g1_lW, g1_lb, g1_rW, g1_rb,
                                       g2_lW, g2_lb, g2_rW, g2_rb, rT, qT);
  k_proj<<<768, 256, 0, stream>>>(hcon, huncon, pW, pb, wsI, H);
  k_tf<<<PA + PB + PC, 256, 0, stream>>>(g1_lW, g1_rW, g2_lW, g2_rW, wsI, H, TA2);
  k_edges<<<1024, 256, 0, stream>>>(edges, H, TA2, H + NM*DD, rT, qT,
                                    g1_cW, g1_cb, g2_cW, g2_cb, lgp);
  k_softmax<<<(NE + 255)/256, 256, 0, stream>>>(edges, lgp, na, out);
  k_rowsum<<<dim3(32, 16), 256, 0, stream>>>(out, bsum);
  k_div<<<(NB*NN + 255)/256, 256, 0, stream>>>(out, bsum);
}